// Round 9
// baseline (99.464 us; speedup 1.0000x reference)
//
#include <hip/hip_runtime.h>
#include <math.h>

// Problem constants (from reference): B=8, C=32, F=32, K=3, H=W=32
#define NB 8
#define NC 32
#define NF 32
#define NH 32
#define NW 32
#define NQ 9
#define CSPLIT 8            // channel chunks; block covers 4 channels
#define CPB 4               // channels per block = ONE PER WAVE
#define TS 34               // padded tile row stride (W+2)
#define TROWS 34            // full padded image rows (32 + 2 halo)
#define TILE_N (TROWS * TS) // 1156 floats per channel tile
#define ALL_N (CPB * TILE_N) // 4624 floats staged per block

typedef float f2 __attribute__((ext_vector_type(2)));
__device__ __forceinline__ f2 sp(float v) { return (f2){v, v}; }

// v7: desynchronized-waves experiment, correctness by construction.
// v6 (wave-private unsynchronized staging) failed correctness; its
// compute math is v5-verified, so the suspect is the barrier-less
// per-wave staging path. v7 keeps the theory under test — a BARRIER-FREE
// main loop where each wave owns one channel end-to-end, so the coeff
// s_load waits of the 4 waves desynchronize instead of phase-locking at
// per-channel __syncthreads (v5 measured: per-row s_load cost is only
// ~15% of runtime; the stall must be simultaneous-wave waits) — but
// stages ALL 4 channel tiles block-cooperatively with LINEAR LDS writes
// (lin[e], e = t + i*256: no exec-mask subtlety, no wave-privacy
// assumption) followed by exactly ONE __syncthreads.
// Cross-channel combine stays HW fp32 atomics (out pre-zeroed).
// LDS 18.5KB/block x 8 blocks/CU = 148KB < 160KB -> 8 blocks/CU kept.
__global__ __launch_bounds__(256, 8) void ka_conv_rational_kernel(
    const float* __restrict__ x,     // [B, C, H, W]
    const float* __restrict__ nums,  // [F*Q*C, 6]
    const float* __restrict__ dens,  // [F*Q*C, 4]
    float* __restrict__ out)         // [B, F, H, W]
{
    __shared__ float tile[CPB][TILE_N]; // 18,496 B

    const int t   = threadIdx.x;
    const int bid = blockIdx.x;          // 0..2047
    const int cs  = bid & (CSPLIT - 1);  // channel chunk
    const int bf  = bid >> 3;            // = b*NF + f, 0..255
    const int f   = bf & (NF - 1);
    const int bb  = bf >> 5;             // / NF
    const int c0  = cs * CPB;

    // ---- block-cooperative staging of all 4 zero-padded channel tiles.
    // Linear LDS fill: element e of the concatenated [4][34][34] buffer.
    const float* __restrict__ xb4 = x + ((size_t)bb * NC + c0) * (NH * NW);
    float* lin = &tile[0][0];
#pragma unroll
    for (int i = 0; i < 19; ++i) {
        int e = t + i * 256;            // 19*256 = 4864 >= 4624
        if (e < ALL_N) {                // i<18 always true; i=18: t<16
            int ch = e / TILE_N;        // magic-mul, prologue-only
            int wi = e - ch * TILE_N;
            int ry = wi / TS;
            int rx = wi - ry * TS;
            int gy = ry - 1, gx = rx - 1;
            bool ok = (gy >= 0) && (gy < NH) && (gx >= 0) && (gx < NW);
            float v = xb4[(ch << 10) + (ok ? gy * NW + gx : 0)]; // clamped
            lin[e] = ok ? v : 0.f;
        }
    }
    __syncthreads(); // the ONLY barrier; waves fully independent after this

    // ---- per-wave compute: wave wv owns channel c0+wv for all pixels ----
    const int lane = t & 63;
    const int wv   = __builtin_amdgcn_readfirstlane(t >> 6); // 0..3
    const int c    = c0 + wv;
    const int xx   = lane & 31;          // output column
    const int hh   = lane >> 5;          // 0/1: top/bottom 16-row half
    const float* tl = tile[wv];

    const size_t rbase = (size_t)f * NQ * NC + c; // coeff row idx at q=0
    float* __restrict__ ob = out + (size_t)bf * NH * NW + xx;

#pragma unroll 1
    for (int g = 0; g < 4; ++g) {
        const int y0 = hh * 16 + g * 4; // first output row of this group

        // 6x3 neighborhood covering the 4 pixels' 3x3 windows
        float n[6][3];
#pragma unroll
        for (int dy = 0; dy < 6; ++dy)
#pragma unroll
            for (int dx = 0; dx < 3; ++dx)
                n[dy][dx] = tl[(y0 + dy) * TS + (xx + dx)];

        f2 acc01 = {0.f, 0.f};
        f2 acc23 = {0.f, 0.f};

#pragma unroll
        for (int q = 0; q < NQ; ++q) {
            // wave-uniform coefficient loads -> scalar (s_load) path
            const float* ap = nums + (rbase + (size_t)q * NC) * 6;
            const float* bp = dens + (rbase + (size_t)q * NC) * 4;
            const float a0 = ap[0], a1 = ap[1], a2 = ap[2],
                        a3 = ap[3], a4 = ap[4], a5 = ap[5];
            const float d0 = bp[0], d1 = bp[1], d2 = bp[2], d3 = bp[3];
            const int qi = q / 3, qj = q - qi * 3;

            f2 w01 = {n[qi][qj],     n[qi + 1][qj]};
            f2 w23 = {n[qi + 2][qj], n[qi + 3][qj]};

            f2 nu01 = __builtin_elementwise_fma(sp(a5), w01, sp(a4));
            f2 nu23 = __builtin_elementwise_fma(sp(a5), w23, sp(a4));
            nu01 = __builtin_elementwise_fma(nu01, w01, sp(a3));
            nu23 = __builtin_elementwise_fma(nu23, w23, sp(a3));
            nu01 = __builtin_elementwise_fma(nu01, w01, sp(a2));
            nu23 = __builtin_elementwise_fma(nu23, w23, sp(a2));
            nu01 = __builtin_elementwise_fma(nu01, w01, sp(a1));
            nu23 = __builtin_elementwise_fma(nu23, w23, sp(a1));
            nu01 = __builtin_elementwise_fma(nu01, w01, sp(a0));
            nu23 = __builtin_elementwise_fma(nu23, w23, sp(a0));

            f2 dp01 = __builtin_elementwise_fma(sp(d3), w01, sp(d2));
            f2 dp23 = __builtin_elementwise_fma(sp(d3), w23, sp(d2));
            dp01 = __builtin_elementwise_fma(dp01, w01, sp(d1));
            dp23 = __builtin_elementwise_fma(dp23, w23, sp(d1));
            dp01 = __builtin_elementwise_fma(dp01, w01, sp(d0));
            dp23 = __builtin_elementwise_fma(dp23, w23, sp(d0));
            dp01 = dp01 * w01;
            dp23 = dp23 * w23;

            f2 de01 = 1.0f + __builtin_elementwise_abs(dp01);
            f2 de23 = 1.0f + __builtin_elementwise_abs(dp23);
            f2 r01 = {__builtin_amdgcn_rcpf(de01.x), __builtin_amdgcn_rcpf(de01.y)};
            f2 r23 = {__builtin_amdgcn_rcpf(de23.x), __builtin_amdgcn_rcpf(de23.y)};
            acc01 = __builtin_elementwise_fma(nu01, r01, acc01);
            acc23 = __builtin_elementwise_fma(nu23, r23, acc23);
        }

        // store this group now: keeps only 4 accumulators live at a time
        float* op = ob + (size_t)y0 * NW;
        unsafeAtomicAdd(op,          acc01.x);
        unsafeAtomicAdd(op + NW,     acc01.y);
        unsafeAtomicAdd(op + 2 * NW, acc23.x);
        unsafeAtomicAdd(op + 3 * NW, acc23.y);
    }
}

extern "C" void kernel_launch(void* const* d_in, const int* in_sizes, int n_in,
                              void* d_out, int out_size, void* d_ws, size_t ws_size,
                              hipStream_t stream) {
    const float* x    = (const float*)d_in[0];
    const float* nums = (const float*)d_in[1];
    const float* dens = (const float*)d_in[2];
    float* out = (float*)d_out;

    // atomic accumulation target must start at zero (harness poisons d_out)
    hipMemsetAsync(d_out, 0, (size_t)out_size * sizeof(float), stream);

    dim3 grid(NB * NF * CSPLIT); // 2048 blocks: (b, f, csplit) -> 8/CU
    dim3 block(256);
    ka_conv_rational_kernel<<<grid, block, 0, stream>>>(x, nums, dens, out);
}

// Round 10
// 82.634 us; speedup vs baseline: 1.2037x; 1.2037x over previous
//
#include <hip/hip_runtime.h>
#include <math.h>

// Problem constants (from reference): B=8, C=32, F=32, K=3, H=W=32
#define NB 8
#define NC 32
#define NF 32
#define NH 32
#define NW 32
#define NQ 9
#define CSPLIT 4            // channel chunks; block covers 8 channels
#define CPB (NC / CSPLIT)   // channels per block = 8
#define TS 34               // padded tile row stride (W+2)
#define TROWS 34            // full padded image rows (32 + 2 halo)
#define TILE_N (TROWS * TS) // 1156
#define CROWS (NQ * CPB)    // 72 coefficient rows per block
#define CROW_F 16           // floats per padded coeff row (a0..5,_,_,d0..3,_x4)

typedef float f2 __attribute__((ext_vector_type(2)));
__device__ __forceinline__ f2 sp(float v) { return (f2){v, v}; }

// v8: remove the VALU instruction fat, keep the proven v5 skeleton.
// Evidence: v7 measured VALUBusy=64% over 46.7us => ~30us of VALU-issue
// time for the same per-wave work as v5 (31.5us kernel) => v5 ran at
// ~95% VALUBusy: VALU-ISSUE-BOUND, not stall-bound. The stream is ~2x
// fatter than ideal; known fat: every Horner step reads TWO distinct
// SGPR coefficients (1-SGPR-per-VALU rule -> ~10 v_mov/iter) plus
// s_load waits. Fix: coefficients staged once into LDS (v4's staging,
// which PASSED correctness; its perf failure was a VGPR spill storm at
// launch_bounds(256,8)'s 64-reg cap). v8 gives the body room:
// __launch_bounds__(256,4) => 128-VGPR cap (hand count ~60, no spill),
// CSPLIT=4 => grid 1024 = 4 blocks/CU in exactly one round.
// Inner-loop coeff access: ds_read_b128/b64 broadcast (conflict-free),
// VGPR-destined (packed ops legal, zero v_mov), immediate offsets,
// prefetchable under lgkmcnt. Compute body = v5's verified math.
__global__ __launch_bounds__(256, 4) void ka_conv_rational_kernel(
    const float* __restrict__ x,     // [B, C, H, W]
    const float* __restrict__ nums,  // [F*Q*C, 6]
    const float* __restrict__ dens,  // [F*Q*C, 4]
    float* __restrict__ out)         // [B, F, H, W]
{
    __shared__ float tile[2][TILE_N];    // 9248 B
    __shared__ float cf[CROWS * CROW_F]; // 4608 B  (13856 B total)

    const int t   = threadIdx.x;
    const int bid = blockIdx.x;          // 0..1023
    const int cs  = bid & (CSPLIT - 1);  // channel chunk
    const int bf  = bid >> 2;            // = b*NF + f, 0..255
    const int f   = bf & (NF - 1);
    const int bb  = bf >> 5;             // / NF
    const int xx  = t & 31;              // output column
    const int ty  = t >> 5;              // 0..7 -> owns rows 4*ty .. 4*ty+3
    const int c0  = cs * CPB;

    // c-invariant staging geometry: element idx of the 34x34 padded tile.
    int  soff[5];
    bool svalid[5];
#pragma unroll
    for (int i = 0; i < 5; ++i) {
        int idx = t + i * 256;
        int ry  = idx / TS;
        int rx  = idx - ry * TS;
        int gy  = ry - 1;
        int gx  = rx - 1;
        bool ok = (idx < TILE_N) && (gy >= 0) && (gy < NH) && (gx >= 0) && (gx < NW);
        svalid[i] = ok;
        soff[i]   = ok ? (gy * NW + gx) : 0; // clamped: always in-bounds
    }

    const float* __restrict__ xb = x + ((size_t)bb * NC + c0) * NH * NW;

    // ---- one-time coefficient staging into LDS (v4's pattern, verified
    // correct there). Covered by the first per-channel barrier below. ----
    if (t < CROWS) {
        const int q = t >> 3, ci = t & (CPB - 1);
        const size_t r = ((size_t)(f * NQ + q)) * NC + (c0 + ci);
        const float* ap = nums + r * 6;      // 24 B, 8-B aligned
        f2 a01 = *(const f2*)ap;
        f2 a23 = *(const f2*)(ap + 2);
        f2 a45 = *(const f2*)(ap + 4);
        float* dst = cf + t * CROW_F;
        *(f2*)(dst)     = a01;
        *(f2*)(dst + 2) = a23;
        *(f2*)(dst + 4) = a45;
    } else if (t >= 128 && t < 128 + CROWS) {
        const int i = t - 128;
        const int q = i >> 3, ci = i & (CPB - 1);
        const size_t r = ((size_t)(f * NQ + q)) * NC + (c0 + ci);
        float4 dd = *(const float4*)(dens + r * 4); // 16 B aligned
        *(float4*)(cf + i * CROW_F + 8) = dd;
    }

    // prefetch first channel into registers
    float st[5];
#pragma unroll
    for (int i = 0; i < 5; ++i)
        st[i] = xb[soff[i]];

    f2 acc01 = {0.f, 0.f};
    f2 acc23 = {0.f, 0.f};

    for (int ci = 0; ci < CPB; ++ci) {
        float* tl = tile[ci & 1];

        // write staged channel (zero-padded) to LDS
#pragma unroll
        for (int i = 0; i < 5; ++i) {
            int idx = t + i * 256;
            if (idx < TILE_N) // i<4 always true; i=4: t<132
                tl[idx] = svalid[i] ? st[i] : 0.f;
        }
        // prefetch next channel (latency hidden behind compute below)
        if (ci + 1 < CPB) {
            const float* xc = xb + (size_t)(ci + 1) * NH * NW;
#pragma unroll
            for (int i = 0; i < 5; ++i)
                st[i] = xc[soff[i]];
        }
        __syncthreads(); // double-buffered: buffer (ci&1) next rewritten at ci+2

        // 6x3 neighborhood covering all 4 pixels' 3x3 windows
        float n[6][3];
#pragma unroll
        for (int dy = 0; dy < 6; ++dy)
#pragma unroll
            for (int dx = 0; dx < 3; ++dx)
                n[dy][dx] = tl[(ty * 4 + dy) * TS + (xx + dx)];

#pragma unroll
        for (int q = 0; q < NQ; ++q) {
            // coeff row from LDS: broadcast ds_read (b128+b64+b128),
            // base = ci*64 B (per-channel), immediate offset q*512 B.
            const float* cp = cf + (q * CPB + ci) * CROW_F;
            float4 A03 = *(const float4*)cp;        // a0 a1 a2 a3
            f2     A45 = *(const f2*)(cp + 4);      // a4 a5
            float4 DD  = *(const float4*)(cp + 8);  // d0 d1 d2 d3
            const int qi = q / 3, qj = q - qi * 3;

            // 4 pixels' terms as two <2 x float> streams (v_pk_* ops)
            f2 w01 = {n[qi][qj],     n[qi + 1][qj]};
            f2 w23 = {n[qi + 2][qj], n[qi + 3][qj]};

            f2 nu01 = __builtin_elementwise_fma(sp(A45.y), w01, sp(A45.x));
            f2 nu23 = __builtin_elementwise_fma(sp(A45.y), w23, sp(A45.x));
            nu01 = __builtin_elementwise_fma(nu01, w01, sp(A03.w));
            nu23 = __builtin_elementwise_fma(nu23, w23, sp(A03.w));
            nu01 = __builtin_elementwise_fma(nu01, w01, sp(A03.z));
            nu23 = __builtin_elementwise_fma(nu23, w23, sp(A03.z));
            nu01 = __builtin_elementwise_fma(nu01, w01, sp(A03.y));
            nu23 = __builtin_elementwise_fma(nu23, w23, sp(A03.y));
            nu01 = __builtin_elementwise_fma(nu01, w01, sp(A03.x));
            nu23 = __builtin_elementwise_fma(nu23, w23, sp(A03.x));

            f2 dp01 = __builtin_elementwise_fma(sp(DD.w), w01, sp(DD.z));
            f2 dp23 = __builtin_elementwise_fma(sp(DD.w), w23, sp(DD.z));
            dp01 = __builtin_elementwise_fma(dp01, w01, sp(DD.y));
            dp23 = __builtin_elementwise_fma(dp23, w23, sp(DD.y));
            dp01 = __builtin_elementwise_fma(dp01, w01, sp(DD.x));
            dp23 = __builtin_elementwise_fma(dp23, w23, sp(DD.x));
            dp01 = dp01 * w01;
            dp23 = dp23 * w23;

            f2 de01 = 1.0f + __builtin_elementwise_abs(dp01);
            f2 de23 = 1.0f + __builtin_elementwise_abs(dp23);
            f2 r01 = {__builtin_amdgcn_rcpf(de01.x), __builtin_amdgcn_rcpf(de01.y)};
            f2 r23 = {__builtin_amdgcn_rcpf(de23.x), __builtin_amdgcn_rcpf(de23.y)};
            acc01 = __builtin_elementwise_fma(nu01, r01, acc01);
            acc23 = __builtin_elementwise_fma(nu23, r23, acc23);
        }
    }

    const int y0 = ty * 4;
    float* op = out + ((size_t)bf * NH + y0) * NW + xx;
    unsafeAtomicAdd(op,          acc01.x);
    unsafeAtomicAdd(op + NW,     acc01.y);
    unsafeAtomicAdd(op + 2 * NW, acc23.x);
    unsafeAtomicAdd(op + 3 * NW, acc23.y);
}

extern "C" void kernel_launch(void* const* d_in, const int* in_sizes, int n_in,
                              void* d_out, int out_size, void* d_ws, size_t ws_size,
                              hipStream_t stream) {
    const float* x    = (const float*)d_in[0];
    const float* nums = (const float*)d_in[1];
    const float* dens = (const float*)d_in[2];
    float* out = (float*)d_out;

    // atomic accumulation target must start at zero (harness poisons d_out)
    hipMemsetAsync(d_out, 0, (size_t)out_size * sizeof(float), stream);

    dim3 grid(NB * NF * CSPLIT); // 1024 blocks: (b, f, csplit) -> 4/CU
    dim3 block(256);
    ka_conv_rational_kernel<<<grid, block, 0, stream>>>(x, nums, dens, out);
}